// Round 1
// baseline (506.459 us; speedup 1.0000x reference)
//
#include <hip/hip_runtime.h>

// MultiheadFeedForward: x[4,4096,2048] fp32; per-head FFN (H=16, dh=128, ff=512)
//   h = relu(x_h @ W1[h] + b1[h]);  out_h = h @ W2[h] + b2[h]
// FP32 global I/O; bf16 MFMA compute. Fused two-GEMM kernel, FF in 4 chunks of
// 128. R5: occupancy fix. R4's structure held xf[4][4]+acc1[4][4]+acc2[4][4]
// = 192 acc/input regs -> ~270 combined VGPR+AGPR -> 1 wave/SIMD (measured
// OccupancyPercent 11.8) -> latency-bound (MfmaUtil 10.8%). Halve the m-tile:
// MT=64, per-wave m=32 -> xf[2][4]+acc1[4][2]+acc2[4][2] = 96 regs, live set
// ~150-165 -> fits __launch_bounds__(256,3) budget (170) spill-free -> 3
// waves/SIMD. Hs halves to 17.4 KB; spend it on a double buffer (34.8 KB,
// same LDS as R4) and drop the trailing barrier per chunk: the one barrier at
// chunk c separates chunk c+1 writes from chunk c-1 reads of the same buffer.

typedef __attribute__((ext_vector_type(8))) short short8;
typedef __attribute__((ext_vector_type(4))) short short4v;
typedef __attribute__((ext_vector_type(2))) short short2v;
typedef __attribute__((ext_vector_type(4))) float f32x4;

#define NHEADS 16
#define DHEAD  128
#define NFF    512
#define DMODEL 2048
#define NTOK   16384
#define MT     64    // token tile per block (R5: halved from 128)
#define FC     128   // ff chunk
#define LPAD   136   // LDS row stride (bf16): 272B = odd*16B -> only free 2-way aliasing

__device__ __forceinline__ short f2bf(float f) {
    unsigned u = __builtin_bit_cast(unsigned, f);
    u += 0x7FFFu + ((u >> 16) & 1u);   // RNE
    return (short)(u >> 16);
}

// Fused transpose+convert for BOTH weight tensors in one launch.
// z = h*2 + which; which=0: W1[h] 128x512 -> w1t[h] 512x128
//                  which=1: W2[h] 512x128 -> w2t[h] 128x512
__global__ __launch_bounds__(256) void transpose_both(
        const float* __restrict__ W1, const float* __restrict__ W2,
        short* __restrict__ w1t, short* __restrict__ w2t) {
    __shared__ short tile[32][33];
    const int z = blockIdx.z;
    const int which = z & 1, h = z >> 1;
    const int R = which ? NFF : DHEAD;      // src rows
    const int C = which ? DHEAD : NFF;      // src cols
    const float* s = (which ? W2 : W1) + (size_t)h * DHEAD * NFF;
    short* d = (which ? w2t : w1t) + (size_t)h * DHEAD * NFF;
    const int t0 = blockIdx.x + 8 * blockIdx.y;  // 0..63 tile id
    const int ctiles = C / 32;
    const int c0 = (t0 % ctiles) * 32, r0 = (t0 / ctiles) * 32;
    const int t = threadIdx.x;
    for (int p = 0; p < 4; ++p) {
        int v = p * 256 + t;
        int r = v >> 5, cc = v & 31;
        tile[r][cc] = f2bf(s[(size_t)(r0 + r) * C + (c0 + cc)]);
    }
    __syncthreads();
    // store: lane -> 2 consecutive r at fixed cc; 16 lanes = 64B contiguous run
    for (int it = 0; it < 2; ++it) {
        int idx = it * 256 + t;
        int l16 = idx & 15, cc = idx >> 4;   // cc 0..31
        int r = l16 * 2;
        short2v v2; v2[0] = tile[r][cc]; v2[1] = tile[r + 1][cc];
        *(short2v*)&d[(size_t)(c0 + cc) * R + r0 + r] = v2;
    }
}

// Grid: (mtile=256, head=16); block 256 (4 waves: wf = f/d half, wm = m half).
// GEMM1: D1[f][m] = W1T(A) x X(B); GEMM2: D2[d][m] = W2T(A) x H(B).
// 16x16x32 bf16 MFMA. A-frag: lane holds A[m'=lane&15][k=quad*8+j].
// B-frag: lane holds B[k=quad*8+j][n=lane&15]. C/D: col=lane&15, row=quad*4+reg.
__global__ __launch_bounds__(256, 3) void ffn_main(
        const float* __restrict__ x,    // [NTOK][DMODEL] fp32
        const short* __restrict__ w1t,  // [H][NFF][DHEAD] bf16 (f, d)
        const float* __restrict__ b1,   // [H][NFF] fp32
        const short* __restrict__ w2t,  // [H][DHEAD][NFF] bf16 (d, f)
        const float* __restrict__ b2,   // [H][DHEAD] fp32
        float* __restrict__ out) {      // [NTOK][DMODEL] fp32
    __shared__ short Hs[2][MT][LPAD];  // double-buffered [m][f_local], 34.8 KB

    const int m0   = blockIdx.x * MT;
    const int h    = blockIdx.y;
    const int tid  = threadIdx.x;
    const int lane = tid & 63;
    const int wave = tid >> 6;
    const int quad = lane >> 4;
    const int l16  = lane & 15;
    const int wf   = wave >> 1;  // f/d half (0/1) of 128
    const int wm   = wave & 1;   // m half (0/1) of 64

    // X as GEMM1 B-operand: lane holds B[k=d][n=m] = x[m][d]. K=128 fixed
    // across chunks -> load fp32 once, keep bf16 in regs (32 VGPRs).
    short8 xf[2][4];  // [mi][kk]
    {
        const float* xb = x + (size_t)(m0 + wm * 32) * DMODEL + h * DHEAD;
        for (int mi = 0; mi < 2; ++mi)
            for (int kk = 0; kk < 4; ++kk) {
                const float* p = xb + (size_t)(mi * 16 + l16) * DMODEL + kk * 32 + quad * 8;
                f32x4 a = *(const f32x4*)(p);
                f32x4 b = *(const f32x4*)(p + 4);
                short8 v;
                v[0] = f2bf(a[0]); v[1] = f2bf(a[1]); v[2] = f2bf(a[2]); v[3] = f2bf(a[3]);
                v[4] = f2bf(b[0]); v[5] = f2bf(b[1]); v[6] = f2bf(b[2]); v[7] = f2bf(b[3]);
                xf[mi][kk] = v;
            }
    }

    f32x4 acc2[4][2];  // [di][mi], persistent across chunks
    for (int di = 0; di < 4; ++di)
        for (int mi = 0; mi < 2; ++mi)
            acc2[di][mi] = (f32x4){0.f, 0.f, 0.f, 0.f};

    // Per-lane weight base pointers (A-frags read 16B at [row=..+l16][col=..+quad*8])
    const short* w1b = w1t + (size_t)h * NFF * DHEAD + (size_t)(wf * 64 + l16) * DHEAD + quad * 8;
    const short* w2b = w2t + (size_t)h * DHEAD * NFF + (size_t)(wf * 64 + l16) * NFF + quad * 8;

    for (int c = 0; c < 4; ++c) {
        const int buf = c & 1;
        // ---- GEMM1: acc1[fi][mi] over k=d (4 steps of 32); W1 frags from global (L2)
        f32x4 acc1[4][2];
        for (int fi = 0; fi < 4; ++fi)
            for (int mi = 0; mi < 2; ++mi)
                acc1[fi][mi] = (f32x4){0.f, 0.f, 0.f, 0.f};
        for (int kk = 0; kk < 4; ++kk) {
            short8 af[4];
            for (int fi = 0; fi < 4; ++fi)
                af[fi] = *(const short8*)(w1b + (size_t)(c * FC + fi * 16) * DHEAD + kk * 32);
            for (int fi = 0; fi < 4; ++fi)
                for (int mi = 0; mi < 2; ++mi)
                    acc1[fi][mi] = __builtin_amdgcn_mfma_f32_16x16x32_bf16(
                        af[fi], xf[mi][kk], acc1[fi][mi], 0, 0, 0);
        }

        // ---- bias + relu -> Hs[buf][m][f] bf16 (packed 8B writes)
        for (int fi = 0; fi < 4; ++fi) {
            f32x4 bb = *(const f32x4*)(b1 + h * NFF + c * FC + wf * 64 + fi * 16 + quad * 4);
            for (int mi = 0; mi < 2; ++mi) {
                int m = wm * 32 + mi * 16 + l16;
                short4v hv;
                for (int r = 0; r < 4; ++r)
                    hv[r] = f2bf(fmaxf(acc1[fi][mi][r] + bb[r], 0.f));
                *(short4v*)&Hs[buf][m][wf * 64 + fi * 16 + quad * 4] = hv;
            }
        }
        // One barrier per chunk: separates this chunk's Hs[buf] writes (above)
        // from its reads (below), AND chunk c+1's writes (to buf^1, after this
        // barrier in program order) from chunk c-1's reads of buf^1 (before it).
        __syncthreads();

        // ---- GEMM2: acc2 += W2T(A) x H(B) over k=f (4 steps of 32); W2 from global
        for (int kk = 0; kk < 4; ++kk) {
            short8 wfr[4], hfr[2];
            for (int di = 0; di < 4; ++di)
                wfr[di] = *(const short8*)(w2b + (size_t)(di * 16) * NFF + c * FC + kk * 32);
            for (int mi = 0; mi < 2; ++mi)
                hfr[mi] = *(const short8*)&Hs[buf][wm * 32 + mi * 16 + l16][kk * 32 + quad * 8];
            for (int di = 0; di < 4; ++di)
                for (int mi = 0; mi < 2; ++mi)
                    acc2[di][mi] = __builtin_amdgcn_mfma_f32_16x16x32_bf16(
                        wfr[di], hfr[mi], acc2[di][mi], 0, 0, 0);
        }
        // no trailing barrier: next chunk writes the other buffer
    }

    // ---- epilogue: out[m][h*128+d] fp32, 16B stores (regs = consecutive d)
    for (int di = 0; di < 4; ++di) {
        f32x4 bb = *(const f32x4*)(b2 + h * DHEAD + wf * 64 + di * 16 + quad * 4);
        for (int mi = 0; mi < 2; ++mi) {
            int m = m0 + wm * 32 + mi * 16 + l16;
            f32x4 ov;
            for (int r = 0; r < 4; ++r)
                ov[r] = acc2[di][mi][r] + bb[r];
            *(f32x4*)(out + (size_t)m * DMODEL + h * DHEAD + wf * 64 + di * 16 + quad * 4) = ov;
        }
    }
}

extern "C" void kernel_launch(void* const* d_in, const int* in_sizes, int n_in,
                              void* d_out, int out_size, void* d_ws, size_t ws_size,
                              hipStream_t stream) {
    const float* x  = (const float*)d_in[0];
    const float* W1 = (const float*)d_in[1];
    const float* b1 = (const float*)d_in[2];
    const float* W2 = (const float*)d_in[3];
    const float* b2 = (const float*)d_in[4];
    float* out = (float*)d_out;

    short* w1t = (short*)d_ws;                                  // [16][512][128] bf16
    short* w2t = (short*)d_ws + (size_t)NHEADS * NFF * DHEAD;   // [16][128][512] bf16

    // Both weight transposes (fp32 -> bf16, [r][c] -> [c][r]) in one launch.
    transpose_both<<<dim3(8, 8, 2 * NHEADS), 256, 0, stream>>>(W1, W2, w1t, w2t);

    ffn_main<<<dim3(NTOK / MT, NHEADS), 256, 0, stream>>>(x, w1t, b1, w2t, b2, out);
}

// Round 2
// 359.046 us; speedup vs baseline: 1.4106x; 1.4106x over previous
//
#include <hip/hip_runtime.h>

// MultiheadFeedForward: x[4,4096,2048] fp32; per-head FFN (H=16, dh=128, ff=512)
//   h = relu(x_h @ W1[h] + b1[h]);  out_h = h @ W2[h] + b2[h]
// R6: canonical staged structure. R4/R5 post-mortem: latency-bound on ~130
// scattered global 16B weight-fragment loads per wave (MfmaUtil 8-11%, all
// pipes idle); occupancy change (R5) didn't help. Fix: weights staged to LDS
// via async global_load_lds (double-buffered W1, W2 hidden under GEMM1),
// counted vmcnt (never 0 in loop), raw s_barrier (no __syncthreads = no
// vmcnt(0) drain). Weight images PRE-SWIZZLED in workspace (XOR granule
// swizzle, T2) so linear glds dest + swizzled ds_read is conflict-free.
// MT=128, 512 threads (8 waves: wf=f/d half, wm=m quarter). LDS 130KB,
// 1 block/CU, 2 waves/SIMD; latency hidden by the async pipeline, not TLP.

typedef __attribute__((ext_vector_type(8))) short short8;
typedef __attribute__((ext_vector_type(4))) short short4v;
typedef __attribute__((ext_vector_type(4))) float f32x4;

#define NHEADS 16
#define DHEAD  128
#define NFF    512
#define DMODEL 2048
#define NTOK   16384
#define MT     128    // token tile per block
#define FC     128    // ff chunk
#define CH_SH  16384  // shorts per 128x128 chunk image (32 KB)

__device__ __forceinline__ short f2bf(float f) {
    unsigned u = __builtin_bit_cast(unsigned, f);
    u += 0x7FFFu + ((u >> 16) & 1u);   // RNE
    return (short)(u >> 16);
}

// async global->LDS, 16B per lane; LDS dest is wave-uniform base (+lane*16 by HW)
#define GLDS16(g, l) __builtin_amdgcn_global_load_lds( \
    (__attribute__((address_space(1))) void*)(g), \
    (__attribute__((address_space(3))) void*)(l), 16, 0, 0)

// Weight prep: fp32 -> bf16, transpose, and write the PRE-SWIZZLED 128x128
// chunk images the main kernel stages linearly.
// Image layout (shorts): [row][ (col_granule ^ (row&7))*8 + col_low3 ]
// which=0: W1[h] src [d=128][f=512] -> w1x[h][c][f_local][d]   (row=f_local)
// which=1: W2[h] src [f=512][d=128] -> w2x[h][c][d][f_local]   (row=d)
__global__ __launch_bounds__(256) void transpose_both(
        const float* __restrict__ W1, const float* __restrict__ W2,
        short* __restrict__ w1x, short* __restrict__ w2x) {
    __shared__ float tile[64][65];
    const int z = blockIdx.z;
    const int which = z & 1, h = z >> 1;
    const int C = which ? DHEAD : NFF;      // src cols
    const float* s = (which ? W2 : W1) + (size_t)h * DHEAD * NFF;
    short* dst = (which ? w2x : w1x) + (size_t)h * 4 * CH_SH;
    const int ct = C / 64;
    const int t0 = blockIdx.x;              // 0..15
    const int r0 = (t0 / ct) * 64, c0 = (t0 % ct) * 64;
    const int t = threadIdx.x;
    #pragma unroll
    for (int p = 0; p < 4; ++p) {
        int idx = p * 256 + t;
        int row = idx >> 4, col = (idx & 15) * 4;
        *(f32x4*)&tile[row][col] = *(const f32x4*)&s[(size_t)(r0 + row) * C + c0 + col];
    }
    __syncthreads();
    #pragma unroll
    for (int it = 0; it < 2; ++it) {
        int u = it * 256 + t;
        int dr = u >> 3, g = u & 7;         // dst row offset, src-row granule
        short8 v;
        #pragma unroll
        for (int j = 0; j < 8; ++j) v[j] = f2bf(tile[g * 8 + j][dr]);
        size_t idx;
        if (which == 0) {                   // dst row = f = c0+dr; col = d
            int f = c0 + dr;
            int gd = (r0 >> 3) + g;
            idx = (size_t)(f >> 7) * CH_SH + (size_t)(f & 127) * 128 + ((gd ^ (f & 7)) << 3);
        } else {                            // dst row = d = c0+dr; col = f_local
            int d = c0 + dr;
            int gf = ((r0 & 127) >> 3) + g;
            idx = (size_t)(r0 >> 7) * CH_SH + (size_t)d * 128 + ((gf ^ (d & 7)) << 3);
        }
        *(short8*)&dst[idx] = v;
    }
}

// Grid (128 mtiles, 16 heads), block 512 (8 waves).
// GEMM1: D1[f][m] = W1T(A) x X(B); GEMM2: D2[d][m] = W2T(A) x H(B).
// A-frag: lane holds A[m'=l16][k=quad*8+j]; B-frag: B[k=quad*8+j][n=l16];
// C/D: col=l16, row=quad*4+reg. All LDS frag reads use the XOR granule swizzle.
__global__ __launch_bounds__(512, 2) void ffn_main(
        const float* __restrict__ x,    // [NTOK][DMODEL] fp32
        const short* __restrict__ w1x,  // [H][4][CH_SH] swizzled bf16
        const float* __restrict__ b1,   // [H][NFF] fp32
        const short* __restrict__ w2x,  // [H][4][CH_SH] swizzled bf16
        const float* __restrict__ b2,   // [H][DHEAD] fp32
        float* __restrict__ out) {      // [NTOK][DMODEL] fp32
    __shared__ short W1s[2][CH_SH];    // 64 KB double-buffered W1 chunk
    __shared__ short W2s[CH_SH];       // 32 KB W2 chunk
    __shared__ short Hs[CH_SH];        // 32 KB hidden tile [m][f_local] swizzled
    __shared__ float Bs[NFF];          // 2 KB bias1

    const int m0   = blockIdx.x * MT;
    const int h    = blockIdx.y;
    const int tid  = threadIdx.x;
    const int lane = tid & 63;
    const int wave = tid >> 6;   // 0..7
    const int quad = lane >> 4;
    const int l16  = lane & 15;
    const int wf   = wave >> 2;  // f/d half (0/1)
    const int wm   = wave & 3;   // m quarter (0..3), 32 rows each
    const int s7   = l16 & 7;

    // bias1 -> LDS (visible after first barrier)
    Bs[tid] = b1[h * NFF + tid];

    // stage W1 chunk 0 (4 x 1KB glds per wave)
    {
        const char* src = (const char*)(w1x + (size_t)h * 4 * CH_SH);
        char* dl = (char*)&W1s[0][0];
        #pragma unroll
        for (int i = 0; i < 4; ++i)
            GLDS16(src + wave * 4096 + i * 1024 + lane * 16, dl + wave * 4096 + i * 1024);
    }

    // X as GEMM1 B-operand, kept bf16 in regs (32 VGPR)
    short8 xf[2][4];  // [mi][kk]
    {
        const float* xb = x + (size_t)(m0 + wm * 32) * DMODEL + h * DHEAD;
        #pragma unroll
        for (int mi = 0; mi < 2; ++mi)
            #pragma unroll
            for (int kk = 0; kk < 4; ++kk) {
                const float* p = xb + (size_t)(mi * 16 + l16) * DMODEL + kk * 32 + quad * 8;
                f32x4 a = *(const f32x4*)(p);
                f32x4 b = *(const f32x4*)(p + 4);
                short8 v;
                v[0] = f2bf(a[0]); v[1] = f2bf(a[1]); v[2] = f2bf(a[2]); v[3] = f2bf(a[3]);
                v[4] = f2bf(b[0]); v[5] = f2bf(b[1]); v[6] = f2bf(b[2]); v[7] = f2bf(b[3]);
                xf[mi][kk] = v;
            }
    }

    f32x4 acc2[4][2];  // [di][mi], persistent across chunks
    #pragma unroll
    for (int di = 0; di < 4; ++di)
        #pragma unroll
        for (int mi = 0; mi < 2; ++mi)
            acc2[di][mi] = (f32x4){0.f, 0.f, 0.f, 0.f};

    const int arow = wf * 64 + l16;   // weight A-frag row base (+fi/di*16)

    #pragma unroll
    for (int c = 0; c < 4; ++c) {
        // issue W2[c] stage (safe: barrier at end of prev chunk)
        {
            const char* src = (const char*)(w2x + ((size_t)h * 4 + c) * CH_SH);
            char* dl = (char*)W2s;
            #pragma unroll
            for (int i = 0; i < 4; ++i)
                GLDS16(src + wave * 4096 + i * 1024 + lane * 16, dl + wave * 4096 + i * 1024);
        }
        // issue W1[c+1] prefetch into the other buffer
        if (c < 3) {
            const char* src = (const char*)(w1x + ((size_t)h * 4 + c + 1) * CH_SH);
            char* dl = (char*)&W1s[(c + 1) & 1][0];
            #pragma unroll
            for (int i = 0; i < 4; ++i)
                GLDS16(src + wave * 4096 + i * 1024 + lane * 16, dl + wave * 4096 + i * 1024);
        }
        // drain W1[c] only (counted): keep W2[c] + W1[c+1] in flight
        if (c < 3) asm volatile("s_waitcnt vmcnt(8) lgkmcnt(0)" ::: "memory");
        else       asm volatile("s_waitcnt vmcnt(4) lgkmcnt(0)" ::: "memory");
        __builtin_amdgcn_s_barrier();

        // ---- GEMM1 from W1s[c&1] + xf regs
        f32x4 acc1[4][2];
        #pragma unroll
        for (int fi = 0; fi < 4; ++fi)
            #pragma unroll
            for (int mi = 0; mi < 2; ++mi)
                acc1[fi][mi] = (f32x4){0.f, 0.f, 0.f, 0.f};
        #pragma unroll
        for (int kk = 0; kk < 4; ++kk) {
            short8 af[4];
            #pragma unroll
            for (int fi = 0; fi < 4; ++fi)
                af[fi] = *(const short8*)&W1s[c & 1][(size_t)(arow + fi * 16) * 128 +
                                                    ((((kk << 2) + quad) ^ s7) << 3)];
            #pragma unroll
            for (int fi = 0; fi < 4; ++fi)
                #pragma unroll
                for (int mi = 0; mi < 2; ++mi)
                    acc1[fi][mi] = __builtin_amdgcn_mfma_f32_16x16x32_bf16(
                        af[fi], xf[mi][kk], acc1[fi][mi], 0, 0, 0);
        }

        // ---- bias + relu -> Hs (swizzled 8B writes)
        #pragma unroll
        for (int fi = 0; fi < 4; ++fi) {
            f32x4 bb = *(const f32x4*)&Bs[c * FC + wf * 64 + fi * 16 + quad * 4];
            #pragma unroll
            for (int mi = 0; mi < 2; ++mi) {
                int mr = wm * 32 + mi * 16 + l16;
                short4v hv;
                #pragma unroll
                for (int r = 0; r < 4; ++r)
                    hv[r] = f2bf(fmaxf(acc1[fi][mi][r] + bb[r], 0.f));
                int g = (wf * 8 + fi * 2 + (quad >> 1)) ^ s7;
                *(short4v*)&Hs[(size_t)mr * 128 + g * 8 + (quad & 1) * 4] = hv;
            }
        }
        // drain W2[c] (keep W1[c+1] in flight) + make Hs writes visible
        if (c < 3) asm volatile("s_waitcnt vmcnt(4) lgkmcnt(0)" ::: "memory");
        else       asm volatile("s_waitcnt vmcnt(0) lgkmcnt(0)" ::: "memory");
        __builtin_amdgcn_s_barrier();

        // ---- GEMM2 from W2s + Hs
        #pragma unroll
        for (int kk = 0; kk < 4; ++kk) {
            short8 wfr[4], hfr[2];
            #pragma unroll
            for (int di = 0; di < 4; ++di)
                wfr[di] = *(const short8*)&W2s[(size_t)(arow + di * 16) * 128 +
                                              ((((kk << 2) + quad) ^ s7) << 3)];
            #pragma unroll
            for (int mi = 0; mi < 2; ++mi)
                hfr[mi] = *(const short8*)&Hs[(size_t)(wm * 32 + mi * 16 + l16) * 128 +
                                             ((((kk << 2) + quad) ^ s7) << 3)];
            #pragma unroll
            for (int di = 0; di < 4; ++di)
                #pragma unroll
                for (int mi = 0; mi < 2; ++mi)
                    acc2[di][mi] = __builtin_amdgcn_mfma_f32_16x16x32_bf16(
                        wfr[di], hfr[mi], acc2[di][mi], 0, 0, 0);
        }
        // end-of-chunk barrier: all GEMM2 reads done before next chunk's stages
        __builtin_amdgcn_s_barrier();
    }

    // ---- epilogue: out[m][h*128+d] fp32, 16B stores
    #pragma unroll
    for (int di = 0; di < 4; ++di) {
        f32x4 bb = *(const f32x4*)(b2 + h * DHEAD + wf * 64 + di * 16 + quad * 4);
        #pragma unroll
        for (int mi = 0; mi < 2; ++mi) {
            int m = m0 + wm * 32 + mi * 16 + l16;
            f32x4 ov;
            #pragma unroll
            for (int r = 0; r < 4; ++r)
                ov[r] = acc2[di][mi][r] + bb[r];
            *(f32x4*)(out + (size_t)m * DMODEL + h * DHEAD + wf * 64 + di * 16 + quad * 4) = ov;
        }
    }
}

extern "C" void kernel_launch(void* const* d_in, const int* in_sizes, int n_in,
                              void* d_out, int out_size, void* d_ws, size_t ws_size,
                              hipStream_t stream) {
    const float* x  = (const float*)d_in[0];
    const float* W1 = (const float*)d_in[1];
    const float* b1 = (const float*)d_in[2];
    const float* W2 = (const float*)d_in[3];
    const float* b2 = (const float*)d_in[4];
    float* out = (float*)d_out;

    short* w1x = (short*)d_ws;                                     // [16][4][CH_SH]
    short* w2x = (short*)d_ws + (size_t)NHEADS * 4 * CH_SH;        // [16][4][CH_SH]

    transpose_both<<<dim3(16, 1, 2 * NHEADS), 256, 0, stream>>>(W1, W2, w1x, w2x);
    ffn_main<<<dim3(NTOK / MT, NHEADS), 512, 0, stream>>>(x, w1x, b1, w2x, b2, out);
}